// Round 2
// 1088.843 us; speedup vs baseline: 1.0317x; 1.0317x over previous
//
#include <hip/hip_runtime.h>

#define HID 128
#define ODIM 64

typedef _Float16 half8 __attribute__((ext_vector_type(8)));
typedef _Float16 half4 __attribute__((ext_vector_type(4)));
typedef float f32x4 __attribute__((ext_vector_type(4)));

// ---------------------------------------------------------------------------
// k_prep: split all GEMM weights into f16 hi/lo planes ONCE, transposed to
// [n][k], K-chunked, rows padded for conflict-free LDS strides.
// Layouts (in halves):
//   WspHi: [L=4][kc=4][n=128][40]   (kp<32 = data, pad = 0)
//   WspLo: [L=4][kc=4][n=128][36]
//   WhHi : [kc=4][n=64][40]
//   WhLo : [kc=4][n=64][36]
// Total 175104 halves = 350208 B of workspace.
// ---------------------------------------------------------------------------
__global__ __launch_bounds__(256) void k_prep(
    const float* __restrict__ Wg, const float* __restrict__ Wout,
    _Float16* __restrict__ WspHi, _Float16* __restrict__ WspLo,
    _Float16* __restrict__ WhHi, _Float16* __restrict__ WhLo) {
  int i = blockIdx.x * 256 + threadIdx.x;
  if (i < 81920) {  // hidden hi
    int kp = i % 40, n = (i / 40) & 127, kc = (i / 5120) & 3, l = i / 20480;
    float v = kp < 32 ? Wg[(size_t)(l * 128 + kc * 32 + kp) * 128 + n] : 0.f;
    WspHi[i] = (_Float16)v;
  } else if (i < 155648) {  // hidden lo
    int j = i - 81920;
    int kp = j % 36, n = (j / 36) & 127, kc = (j / 4608) & 3, l = j / 18432;
    float v = kp < 32 ? Wg[(size_t)(l * 128 + kc * 32 + kp) * 128 + n] : 0.f;
    _Float16 h = (_Float16)v;
    WspLo[j] = (_Float16)(v - (float)h);
  } else if (i < 165888) {  // head hi
    int j = i - 155648;
    int kp = j % 40, n = (j / 40) & 63, kc = j / 2560;
    float v = kp < 32 ? Wout[(kc * 32 + kp) * 64 + n] : 0.f;
    WhHi[j] = (_Float16)v;
  } else if (i < 175104) {  // head lo
    int j = i - 165888;
    int kp = j % 36, n = (j / 36) & 63, kc = j / 2304;
    float v = kp < 32 ? Wout[(kc * 32 + kp) * 64 + n] : 0.f;
    _Float16 h = (_Float16)v;
    WhLo[j] = (_Float16)(v - (float)h);
  }
}

// ---------------------------------------------------------------------------
// Encode: x0[n][c] = relu(Win[color][c] + fr*Win[10][c] + fc*Win[11][c] + bin[c])
// ---------------------------------------------------------------------------
__global__ __launch_bounds__(256) void k_encode(
    const int* __restrict__ grids, const float* __restrict__ Win,
    const float* __restrict__ binp, float* __restrict__ X, int b0, int nodes) {
  int t = blockIdx.x * 256 + threadIdx.x;
  if (t >= nodes * 32) return;
  int node = t >> 5;
  int i = t & 31;
  int n = node % 900;
  int b = node / 900;
  int r = n / 30, c = n - r * 30;
  int color = grids[(b0 + b) * 900 + n];
  float fr = (float)r / 29.0f, fc = (float)c / 29.0f;
  f32x4 wc = ((const f32x4*)(Win + color * HID))[i];
  f32x4 wr = ((const f32x4*)(Win + 10 * HID))[i];
  f32x4 wl = ((const f32x4*)(Win + 11 * HID))[i];
  f32x4 bb = ((const f32x4*)binp)[i];
  f32x4 v = wc + fr * wr + fc * wl + bb;
#pragma unroll
  for (int j = 0; j < 4; ++j) v[j] = fmaxf(v[j], 0.0f);
  ((f32x4*)(X + (size_t)node * HID))[i] = v;
}

// ---------------------------------------------------------------------------
// Fused GCN layer v3: Xout = relu(LN((A·Xin)@W + bg)) + Xin
//
// Changes vs v2 (which was latency/barrier-bound: no pipe >33% busy,
// occupancy 32.6%):
//  - M=256 tile, 512-thread (8-wave) blocks: halo overhead 1.47x -> 1.23x,
//    W-staging & barrier count per output row halved.
//  - W arrives pre-split/pre-transposed/pre-padded from k_prep: in-loop W
//    staging is a pure linear f32x4 copy (no strided loads, no cvt VALU, no
//    4-way-conflicted half2 LDS writes -> was ~40% of SQ_LDS_BANK_CONFLICT).
//  - LDS 45504(Xt 316x36) + 10240(Whi 128x40) + 9216(Wlo 128x36) = 64960 B
//    <= 64 KB -> 2 blocks/CU = 16 waves/CU (was 10.4).
//  - stencil row offsets folded into one base VGPR + ds_read immediates.
// Numerics identical to v2 (same split, same MFMA order).
// ---------------------------------------------------------------------------
__global__ __launch_bounds__(512, 4) void k_hidden(
    const float* __restrict__ Xin, float* __restrict__ Xout,
    const _Float16* __restrict__ Whi, const _Float16* __restrict__ Wlo,
    const float* __restrict__ bgp, const float* __restrict__ gamp,
    const float* __restrict__ betp, int nodesTotal) {
  constexpr int XTS = 36;    // Xt row stride in dwords (conflict-free, 16B rows)
  constexpr int XROWS = 316; // 256 + 2*30 halo
  __shared__ __attribute__((aligned(16))) float Xt[XROWS * XTS];     // 45504 B
  __shared__ __attribute__((aligned(16))) _Float16 WThi[128 * 40];   // 10240 B
  __shared__ __attribute__((aligned(16))) _Float16 WTlo[128 * 36];   //  9216 B

  const int t = threadIdx.x;
  const int lane = t & 63;
  const int wave = t >> 6;
  const int q = lane >> 4, l16 = lane & 15;
  const int blockRow0 = blockIdx.x * 256;
  const int waveRow0 = blockRow0 + wave * 32;

  // Stencil: one LDS base per M-tile (corner = up-neighbor row), neighbors
  // via compile-time dword offsets: up=0, left=1044, self=1080, right=1116,
  // down=2160. Invalid directions get weight 0 (staged data is clamped-finite).
  int xb[2];
  float wts[2][5];
#pragma unroll
  for (int mt = 0; mt < 2; ++mt) {
    int nd = waveRow0 + mt * 16 + l16;
    if (nd > nodesTotal - 1) nd = nodesTotal - 1;
    int n = nd % 900;
    int r = n / 30, c = n - r * 30;
    int loc = nd - blockRow0 + 30;  // in [30, 285]
    xb[mt] = (loc - 30) * XTS;
    float dc = rsqrtf((float)(1 + (r > 0) + (r < 29) + (c > 0) + (c < 29)));
    wts[mt][0] = dc * dc;
    wts[mt][1] = (r > 0) ? dc * rsqrtf((float)(2 + (r > 1) + (c > 0) + (c < 29))) : 0.f;
    wts[mt][2] = (r < 29) ? dc * rsqrtf((float)(2 + (r < 28) + (c > 0) + (c < 29))) : 0.f;
    wts[mt][3] = (c > 0) ? dc * rsqrtf((float)(2 + (r > 0) + (r < 29) + (c > 1))) : 0.f;
    wts[mt][4] = (c < 29) ? dc * rsqrtf((float)(2 + (r > 0) + (r < 29) + (c < 28))) : 0.f;
  }

  f32x4 acc[2][8];
#pragma unroll
  for (int mt = 0; mt < 2; ++mt)
#pragma unroll
    for (int nt = 0; nt < 8; ++nt) acc[mt][nt] = (f32x4){0.f, 0.f, 0.f, 0.f};

  for (int kc = 0; kc < 4; ++kc) {
    __syncthreads();  // previous iteration's LDS fully consumed
    // ---- stage X tile (coalesced f32x4), rows clamped into [0, nodesTotal)
    for (int f = t; f < XROWS * 8; f += 512) {
      int row = f >> 3, v = f & 7;
      int gr = blockRow0 - 30 + row;
      gr = gr < 0 ? 0 : (gr > nodesTotal - 1 ? nodesTotal - 1 : gr);
      *(f32x4*)(Xt + row * XTS + v * 4) =
          *(const f32x4*)(Xin + (size_t)gr * HID + kc * 32 + v * 4);
    }
    // ---- stage W K-chunk: pure linear copies from pre-split planes (L2-hot)
    {
      const f32x4* hs = (const f32x4*)(Whi + kc * 5120);
      for (int f = t; f < 640; f += 512) ((f32x4*)WThi)[f] = hs[f];
      const f32x4* ls = (const f32x4*)(Wlo + kc * 4608);
      for (int f = t; f < 576; f += 512) ((f32x4*)WTlo)[f] = ls[f];
    }
    __syncthreads();

    // ---- A fragments: 5-point stencil from LDS, split f16 hi/lo
    half8 Ahi[2], Alo[2];
#pragma unroll
    for (int mt = 0; mt < 2; ++mt) {
      const float* x0 = Xt + xb[mt] + q * 8;
      f32x4 s0 = wts[mt][0] * (*(const f32x4*)(x0 + 1080));
      f32x4 s1 = wts[mt][0] * (*(const f32x4*)(x0 + 1084));
      s0 += wts[mt][1] * (*(const f32x4*)(x0 + 0));
      s1 += wts[mt][1] * (*(const f32x4*)(x0 + 4));
      s0 += wts[mt][2] * (*(const f32x4*)(x0 + 2160));
      s1 += wts[mt][2] * (*(const f32x4*)(x0 + 2164));
      s0 += wts[mt][3] * (*(const f32x4*)(x0 + 1044));
      s1 += wts[mt][3] * (*(const f32x4*)(x0 + 1048));
      s0 += wts[mt][4] * (*(const f32x4*)(x0 + 1116));
      s1 += wts[mt][4] * (*(const f32x4*)(x0 + 1120));
#pragma unroll
      for (int j = 0; j < 4; ++j) {
        _Float16 h0 = (_Float16)s0[j];
        Ahi[mt][j] = h0;
        Alo[mt][j] = (_Float16)(s0[j] - (float)h0);
        _Float16 h1 = (_Float16)s1[j];
        Ahi[mt][4 + j] = h1;
        Alo[mt][4 + j] = (_Float16)(s1[j] - (float)h1);
      }
    }
    // ---- B fragments + MFMA (hi stride 40 -> b128; lo stride 36 -> 2x b64)
    const int kb = q * 8;
#pragma unroll
    for (int nt = 0; nt < 8; ++nt) {
      int n = nt * 16 + l16;
      half8 bhi = *(const half8*)(WThi + n * 40 + kb);
      half4 b0 = *(const half4*)(WTlo + n * 36 + kb);
      half4 b1 = *(const half4*)(WTlo + n * 36 + kb + 4);
      half8 blo;
#pragma unroll
      for (int j = 0; j < 4; ++j) { blo[j] = b0[j]; blo[4 + j] = b1[j]; }
#pragma unroll
      for (int mt = 0; mt < 2; ++mt) {
        acc[mt][nt] = __builtin_amdgcn_mfma_f32_16x16x32_f16(Alo[mt], bhi, acc[mt][nt], 0, 0, 0);
        acc[mt][nt] = __builtin_amdgcn_mfma_f32_16x16x32_f16(Ahi[mt], blo, acc[mt][nt], 0, 0, 0);
        acc[mt][nt] = __builtin_amdgcn_mfma_f32_16x16x32_f16(Ahi[mt], bhi, acc[mt][nt], 0, 0, 0);
      }
    }
  }

  // ---- epilogue: bias + LN + relu + residual, direct store from C/D layout
  float bgv[8], gv[8], btv[8];
#pragma unroll
  for (int nt = 0; nt < 8; ++nt) {
    int cl = nt * 16 + l16;
    bgv[nt] = bgp[cl];
    gv[nt] = gamp[cl];
    btv[nt] = betp[cl];
  }
#pragma unroll
  for (int mt = 0; mt < 2; ++mt) {
#pragma unroll
    for (int reg = 0; reg < 4; ++reg) {
      float rs = 0.f;
#pragma unroll
      for (int nt = 0; nt < 8; ++nt) {
        acc[mt][nt][reg] += bgv[nt];
        rs += acc[mt][nt][reg];
      }
      rs += __shfl_xor(rs, 1, 64);
      rs += __shfl_xor(rs, 2, 64);
      rs += __shfl_xor(rs, 4, 64);
      rs += __shfl_xor(rs, 8, 64);
      float mean = rs * (1.f / 128.f);
      float ss = 0.f;
#pragma unroll
      for (int nt = 0; nt < 8; ++nt) {
        float d = acc[mt][nt][reg] - mean;
        ss += d * d;
      }
      ss += __shfl_xor(ss, 1, 64);
      ss += __shfl_xor(ss, 2, 64);
      ss += __shfl_xor(ss, 4, 64);
      ss += __shfl_xor(ss, 8, 64);
      float rsd = rsqrtf(ss * (1.f / 128.f) + 1e-5f);
      int row = waveRow0 + mt * 16 + q * 4 + reg;  // uniform across the 16-lane group
      if (row < nodesTotal) {
        const float* xr = Xin + (size_t)row * HID;
        float* xo = Xout + (size_t)row * HID;
#pragma unroll
        for (int nt = 0; nt < 8; ++nt) {
          int col = nt * 16 + l16;
          float y = fmaxf((acc[mt][nt][reg] - mean) * rsd * gv[nt] + btv[nt], 0.f);
          xo[col] = y + xr[col];
        }
      }
    }
  }
}

// ---------------------------------------------------------------------------
// Head v3: Out = Xin @ Wout + bout (pre-split W, M=256, 512 threads)
// ---------------------------------------------------------------------------
__global__ __launch_bounds__(512, 6) void k_head(
    const float* __restrict__ Xin, float* __restrict__ Out,
    const _Float16* __restrict__ Whi, const _Float16* __restrict__ Wlo,
    const float* __restrict__ bp, int nodesTotal) {
  constexpr int XTS = 36;
  __shared__ __attribute__((aligned(16))) float Xt[256 * XTS];     // 36864 B
  __shared__ __attribute__((aligned(16))) _Float16 WThi[64 * 40];  //  5120 B
  __shared__ __attribute__((aligned(16))) _Float16 WTlo[64 * 36];  //  4608 B

  const int t = threadIdx.x;
  const int lane = t & 63;
  const int wave = t >> 6;
  const int q = lane >> 4, l16 = lane & 15;
  const int blockRow0 = blockIdx.x * 256;
  const int waveRow0 = blockRow0 + wave * 32;

  int xb[2];
#pragma unroll
  for (int mt = 0; mt < 2; ++mt) {
    int nd = waveRow0 + mt * 16 + l16;
    if (nd > nodesTotal - 1) nd = nodesTotal - 1;
    xb[mt] = (nd - blockRow0) * XTS;
  }

  f32x4 acc[2][4];
#pragma unroll
  for (int mt = 0; mt < 2; ++mt)
#pragma unroll
    for (int nt = 0; nt < 4; ++nt) acc[mt][nt] = (f32x4){0.f, 0.f, 0.f, 0.f};

  for (int kc = 0; kc < 4; ++kc) {
    __syncthreads();
    for (int f = t; f < 256 * 8; f += 512) {
      int row = f >> 3, v = f & 7;
      int gr = blockRow0 + row;
      if (gr > nodesTotal - 1) gr = nodesTotal - 1;
      *(f32x4*)(Xt + row * XTS + v * 4) =
          *(const f32x4*)(Xin + (size_t)gr * HID + kc * 32 + v * 4);
    }
    {
      const f32x4* hs = (const f32x4*)(Whi + kc * 2560);
      for (int f = t; f < 320; f += 512) ((f32x4*)WThi)[f] = hs[f];
      const f32x4* ls = (const f32x4*)(Wlo + kc * 2304);
      for (int f = t; f < 288; f += 512) ((f32x4*)WTlo)[f] = ls[f];
    }
    __syncthreads();

    half8 Ahi[2], Alo[2];
#pragma unroll
    for (int mt = 0; mt < 2; ++mt) {
      const float* xp = Xt + xb[mt] + q * 8;
      f32x4 s0 = *(const f32x4*)xp;
      f32x4 s1 = *(const f32x4*)(xp + 4);
#pragma unroll
      for (int j = 0; j < 4; ++j) {
        _Float16 h0 = (_Float16)s0[j];
        Ahi[mt][j] = h0;
        Alo[mt][j] = (_Float16)(s0[j] - (float)h0);
        _Float16 h1 = (_Float16)s1[j];
        Ahi[mt][4 + j] = h1;
        Alo[mt][4 + j] = (_Float16)(s1[j] - (float)h1);
      }
    }
    const int kb = q * 8;
#pragma unroll
    for (int nt = 0; nt < 4; ++nt) {
      int n = nt * 16 + l16;
      half8 bhi = *(const half8*)(WThi + n * 40 + kb);
      half4 b0 = *(const half4*)(WTlo + n * 36 + kb);
      half4 b1 = *(const half4*)(WTlo + n * 36 + kb + 4);
      half8 blo;
#pragma unroll
      for (int j = 0; j < 4; ++j) { blo[j] = b0[j]; blo[4 + j] = b1[j]; }
#pragma unroll
      for (int mt = 0; mt < 2; ++mt) {
        acc[mt][nt] = __builtin_amdgcn_mfma_f32_16x16x32_f16(Alo[mt], bhi, acc[mt][nt], 0, 0, 0);
        acc[mt][nt] = __builtin_amdgcn_mfma_f32_16x16x32_f16(Ahi[mt], blo, acc[mt][nt], 0, 0, 0);
        acc[mt][nt] = __builtin_amdgcn_mfma_f32_16x16x32_f16(Ahi[mt], bhi, acc[mt][nt], 0, 0, 0);
      }
    }
  }

  float bv[4];
#pragma unroll
  for (int nt = 0; nt < 4; ++nt) bv[nt] = bp[nt * 16 + l16];
#pragma unroll
  for (int mt = 0; mt < 2; ++mt) {
#pragma unroll
    for (int reg = 0; reg < 4; ++reg) {
      int row = waveRow0 + mt * 16 + q * 4 + reg;
      if (row < nodesTotal) {
        float* op = Out + (size_t)row * ODIM;
#pragma unroll
        for (int nt = 0; nt < 4; ++nt)
          op[nt * 16 + l16] = acc[mt][nt][reg] + bv[nt];
      }
    }
  }
}

// ---------------------------------------------------------------------------
extern "C" void kernel_launch(void* const* d_in, const int* in_sizes, int n_in,
                              void* d_out, int out_size, void* d_ws, size_t ws_size,
                              hipStream_t stream) {
  const int* grids = (const int*)d_in[0];
  // d_in[1] = edge_index: unused (fixed 30x30 grid + self-loops, analytic coefs)
  const float* Win  = (const float*)d_in[2];
  const float* bin  = (const float*)d_in[3];
  const float* Wg   = (const float*)d_in[4];
  const float* bg   = (const float*)d_in[5];
  const float* gam  = (const float*)d_in[6];
  const float* bet  = (const float*)d_in[7];
  const float* Wout = (const float*)d_in[8];
  const float* bout = (const float*)d_in[9];
  float* Out = (float*)d_out;

  // workspace: [pre-split W (350208 B) | Xa | Xb]
  _Float16* WspHi = (_Float16*)d_ws;
  _Float16* WspLo = WspHi + 81920;
  _Float16* WhHi  = WspHi + 155648;
  _Float16* WhLo  = WspHi + 165888;
  const size_t wBytes = 350208;

  const int Btot = 512;
  const size_t perBatchBytes = (size_t)900 * HID * 4 * 2;  // ping-pong X buffers
  size_t xws = ws_size > wBytes ? ws_size - wBytes : 0;
  int chunkB = (int)(xws / perBatchBytes);
  if (chunkB > Btot) chunkB = Btot;
  if (chunkB < 1) chunkB = 1;
  int nch = (Btot + chunkB - 1) / chunkB;

  float* Xa = (float*)((char*)d_ws + wBytes);
  float* Xb = Xa + (size_t)chunkB * 900 * HID;

  k_prep<<<dim3(684), dim3(256), 0, stream>>>(Wg, Wout, WspHi, WspLo, WhHi, WhLo);

  for (int ci = 0; ci < nch; ++ci) {
    int b0 = ci * chunkB;
    int cb = Btot - b0;
    if (cb > chunkB) cb = chunkB;
    int nodes = cb * 900;
    int gb = (nodes + 255) / 256;

    k_encode<<<dim3((nodes * 32 + 255) / 256), dim3(256), 0, stream>>>(
        grids, Win, bin, Xa, b0, nodes);
    float* src = Xa;
    float* dst = Xb;
    for (int l = 0; l < 4; ++l) {
      k_hidden<<<dim3(gb), dim3(512), 0, stream>>>(
          src, dst, WspHi + l * 20480, WspLo + l * 18432,
          bg + l * HID, gam + l * HID, bet + l * HID, nodes);
      float* tmp = src; src = dst; dst = tmp;
    }
    // after 4 swaps the final X is back in Xa
    k_head<<<dim3(gb), dim3(512), 0, stream>>>(
        src, Out + (size_t)b0 * 900 * ODIM, WhHi, WhLo, bout, nodes);
  }
}